// Round 1
// baseline (135.897 us; speedup 1.0000x reference)
//
#include <hip/hip_runtime.h>
#include <math.h>

#define NB 2
#define SS 256
#define DD 768
#define NH 12
#define WW 64
#define NSROWS (NB * SS)        // 512
#define ROWS 8                  // rows of Q per attention block

constexpr float PIR = 1.5707963267948966f;   // pi * R, R = 0.5

// ---------------- QKV projection: y = x @ W^T + b, stored (B,H,S,W) ----------------
__global__ __launch_bounds__(256) void qkv_gemm(
    const float* __restrict__ x,
    const float* __restrict__ Wq, const float* __restrict__ bq,
    const float* __restrict__ Wk, const float* __restrict__ bk,
    const float* __restrict__ Wv, const float* __restrict__ bv,
    float* __restrict__ ws)
{
    const int which = blockIdx.z;
    const float* Wm   = (which == 0) ? Wq : (which == 1) ? Wk : Wv;
    const float* bias = (which == 0) ? bq : (which == 1) ? bk : bv;
    float* out = ws + (size_t)which * (NB * NH * SS * WW);

    // K-major tiles: [k][n] so compute reads are contiguous float4
    __shared__ float xs[16][64];
    __shared__ float wsm[16][64];

    const int tid = threadIdx.x;
    const int tx = tid & 15;
    const int ty = tid >> 4;
    const int row0 = blockIdx.x * 64;   // n base (b*S+s)
    const int col0 = blockIdx.y * 64;   // j base (output dim) -- one head per block

    const int lr = tid >> 2;            // 0..63 staging row
    const int lc = (tid & 3) * 4;       // 0,4,8,12 staging col

    float acc[4][4];
    #pragma unroll
    for (int i = 0; i < 4; ++i)
        #pragma unroll
        for (int j = 0; j < 4; ++j) acc[i][j] = 0.f;

    for (int k0 = 0; k0 < DD; k0 += 16) {
        float4 xv = *reinterpret_cast<const float4*>(&x[(size_t)(row0 + lr) * DD + k0 + lc]);
        float4 wv = *reinterpret_cast<const float4*>(&Wm[(size_t)(col0 + lr) * DD + k0 + lc]);
        __syncthreads();
        xs[lc + 0][lr] = xv.x; xs[lc + 1][lr] = xv.y; xs[lc + 2][lr] = xv.z; xs[lc + 3][lr] = xv.w;
        wsm[lc + 0][lr] = wv.x; wsm[lc + 1][lr] = wv.y; wsm[lc + 2][lr] = wv.z; wsm[lc + 3][lr] = wv.w;
        __syncthreads();
        #pragma unroll
        for (int kk = 0; kk < 16; ++kk) {
            float4 a = *reinterpret_cast<const float4*>(&xs[kk][ty * 4]);
            float4 b = *reinterpret_cast<const float4*>(&wsm[kk][tx * 4]);
            float av[4] = {a.x, a.y, a.z, a.w};
            float bvv[4] = {b.x, b.y, b.z, b.w};
            #pragma unroll
            for (int mi = 0; mi < 4; ++mi)
                #pragma unroll
                for (int ni = 0; ni < 4; ++ni)
                    acc[mi][ni] = fmaf(av[mi], bvv[ni], acc[mi][ni]);
        }
    }

    const int hh = col0 >> 6;   // head index (col0 is a multiple of 64)
    #pragma unroll
    for (int mi = 0; mi < 4; ++mi) {
        int n  = row0 + ty * 4 + mi;
        int b_ = n >> 8;          // / 256
        int s_ = n & 255;
        float* orow = out + (((size_t)b_ * NH + hh) * SS + s_) * WW;
        #pragma unroll
        for (int ni = 0; ni < 4; ++ni) {
            int j = col0 + tx * 4 + ni;
            orow[j & 63] = acc[mi][ni] + bias[j];
        }
    }
}

// ---------------- Fourier attention ----------------
// grid: (S/ROWS, B*H); block 256 (4 waves). Each wave handles 2 Q rows.
__global__ __launch_bounds__(256) void fattn(
    const float* __restrict__ ws,
    const float* __restrict__ mask,
    float* __restrict__ out)
{
    const int bh = blockIdx.y;
    const int b  = bh / NH;
    const int h  = bh % NH;
    const int row_base = blockIdx.x * ROWS;

    const float* Qg = ws + (size_t)bh * (SS * WW);
    const float* Kg = ws + (size_t)(NB * NH * SS * WW)     + (size_t)bh * (SS * WW);
    const float* Vg = ws + (size_t)(2 * NB * NH * SS * WW) + (size_t)bh * (SS * WW);

    __shared__ float Kt[WW][SS];     // 64 KiB, transposed, pre-scaled by PIR
    __shared__ float Vs[SS][WW];     // 64 KiB
    __shared__ float Qs[ROWS][WW];   // 2 KiB, pre-scaled by PIR
    __shared__ float mterm[SS];      // 1 KiB
    __shared__ float ebuf[4][SS];    // 4 KiB (per-wave exp buffer)

    const int tid  = threadIdx.x;
    const int lane = tid & 63;
    const int wid  = tid >> 6;

    // ---- stage V (flat) and K (transposed, scaled) ----
    const float4* K4 = reinterpret_cast<const float4*>(Kg);
    const float4* V4 = reinterpret_cast<const float4*>(Vg);
    float4* Vs4 = reinterpret_cast<float4*>(&Vs[0][0]);
    for (int idx4 = tid; idx4 < SS * WW / 4; idx4 += 256) {
        Vs4[idx4] = V4[idx4];
        float4 kv = K4[idx4];
        int idx = idx4 * 4;
        int i = idx >> 6;
        int w = idx & 63;
        Kt[w + 0][i] = PIR * kv.x;
        Kt[w + 1][i] = PIR * kv.y;
        Kt[w + 2][i] = PIR * kv.z;
        Kt[w + 3][i] = PIR * kv.w;
    }
    // stage Q rows (scaled)
    {
        const float4* Q4 = reinterpret_cast<const float4*>(Qg + (size_t)row_base * WW);
        float4* Qs4 = reinterpret_cast<float4*>(&Qs[0][0]);
        if (tid < ROWS * WW / 4) {
            float4 qv = Q4[tid];
            qv.x *= PIR; qv.y *= PIR; qv.z *= PIR; qv.w *= PIR;
            Qs4[tid] = qv;
        }
    }
    // mask additive term
    mterm[tid] = -10000.0f * (1.0f - mask[b * SS + tid]);
    __syncthreads();

    for (int rr = 0; rr < ROWS / 4; ++rr) {
        const int l = wid * (ROWS / 4) + rr;   // local Q row for this wave

        // ---- scores: lane owns key index i = ib*64+lane ----
        float p[4][2];
        #pragma unroll
        for (int ib = 0; ib < 4; ++ib) { p[ib][0] = 1.f; p[ib][1] = 1.f; }

        #pragma unroll 8
        for (int w = 0; w < WW; ++w) {
            float qv = Qs[l][w];               // uniform -> LDS broadcast
            #pragma unroll
            for (int ib = 0; ib < 4; ++ib) {
                float t = qv - Kt[w][ib * 64 + lane];   // = pi*R*(q-k)
                float u;
                if (fabsf(t) < 1e-30f) u = 1.0f;
                else u = __sinf(t) * __builtin_amdgcn_rcpf(t);
                float u2 = u * u;
                p[ib][w & 1] *= u2 * u2;
            }
        }
        float sc[4];
        #pragma unroll
        for (int ib = 0; ib < 4; ++ib)
            sc[ib] = p[ib][0] * p[ib][1] + mterm[ib * 64 + lane];

        // ---- softmax over 256 values (4 per lane) ----
        float m = fmaxf(fmaxf(sc[0], sc[1]), fmaxf(sc[2], sc[3]));
        #pragma unroll
        for (int off = 32; off > 0; off >>= 1)
            m = fmaxf(m, __shfl_xor(m, off));
        float e[4];
        float Z = 0.f;
        #pragma unroll
        for (int ib = 0; ib < 4; ++ib) { e[ib] = __expf(sc[ib] - m); Z += e[ib]; }
        #pragma unroll
        for (int off = 32; off > 0; off >>= 1)
            Z += __shfl_xor(Z, off);

        #pragma unroll
        for (int ib = 0; ib < 4; ++ib) ebuf[wid][ib * 64 + lane] = e[ib];
        __syncthreads();   // orders the per-wave LDS write->read (uniform across waves)

        // ---- y[w=lane] = (sum_i e_i * V[i][lane]) / Z ----
        float y = 0.f;
        const float4* eb4 = reinterpret_cast<const float4*>(&ebuf[wid][0]);
        #pragma unroll 4
        for (int i4 = 0; i4 < SS / 4; ++i4) {
            float4 ee = eb4[i4];
            int i = i4 * 4;
            y = fmaf(ee.x, Vs[i + 0][lane], y);
            y = fmaf(ee.y, Vs[i + 1][lane], y);
            y = fmaf(ee.z, Vs[i + 2][lane], y);
            y = fmaf(ee.w, Vs[i + 3][lane], y);
        }
        y *= __builtin_amdgcn_rcpf(Z);

        const int srow = row_base + l;
        out[((size_t)b * SS + srow) * DD + h * WW + lane] = y;
    }
}

extern "C" void kernel_launch(void* const* d_in, const int* in_sizes, int n_in,
                              void* d_out, int out_size, void* d_ws, size_t ws_size,
                              hipStream_t stream) {
    const float* x    = (const float*)d_in[0];
    const float* mask = (const float*)d_in[1];
    const float* Wq   = (const float*)d_in[2];
    const float* bq   = (const float*)d_in[3];
    const float* Wk   = (const float*)d_in[4];
    const float* bk   = (const float*)d_in[5];
    const float* Wv   = (const float*)d_in[6];
    const float* bv   = (const float*)d_in[7];
    float* out = (float*)d_out;
    float* ws  = (float*)d_ws;    // Q | K | V, each (B,H,S,W) f32 = 1.5 MiB

    dim3 g1(NSROWS / 64, DD / 64, 3);
    qkv_gemm<<<g1, 256, 0, stream>>>(x, Wq, bq, Wk, bk, Wv, bv, ws);

    dim3 g2(SS / ROWS, NB * NH);
    fattn<<<g2, 256, 0, stream>>>(ws, mask, out);
}

// Round 2
// 110.931 us; speedup vs baseline: 1.2251x; 1.2251x over previous
//
#include <hip/hip_runtime.h>
#include <math.h>

#define NB 2
#define SS 256
#define DD 768
#define NH 12
#define WW 64
#define NSROWS (NB * SS)        // 512
#define ROWS_B 8                // Q rows per attention block

constexpr float PIR = 1.5707963267948966f;   // pi * R, R = 0.5

// ---------------- QKV projection: y = x @ W^T + b, stored (B,H,S,W) ----------------
// 64x32 tile, 256 threads, 8 outputs/thread -> grid (8,24,3)=576 blocks (2.25 w/SIMD)
__global__ __launch_bounds__(256) void qkv_gemm(
    const float* __restrict__ x,
    const float* __restrict__ Wq, const float* __restrict__ bq,
    const float* __restrict__ Wk, const float* __restrict__ bk,
    const float* __restrict__ Wv, const float* __restrict__ bv,
    float* __restrict__ ws)
{
    const int which = blockIdx.z;
    const float* Wm   = (which == 0) ? Wq : (which == 1) ? Wk : Wv;
    const float* bias = (which == 0) ? bq : (which == 1) ? bk : bv;
    float* outp = ws + (size_t)which * (NB * NH * SS * WW);

    __shared__ __align__(16) float xs[16][64];
    __shared__ __align__(16) float wsm[16][32];

    const int tid = threadIdx.x;
    const int tx = tid & 15;            // col pair: cols tx*2 .. tx*2+1
    const int ty = tid >> 4;            // row quad: rows ty*4 .. ty*4+3
    const int row0 = blockIdx.x * 64;
    const int col0 = blockIdx.y * 32;

    const int lr = tid >> 2;            // 0..63 x-staging row
    const int lc = (tid & 3) * 4;       // 0,4,8,12 k offset
    const int wr = tid >> 2;            // 0..31 w-staging row (tid<128)
    const int wc = (tid & 3) * 4;

    float acc[4][2] = {};

    for (int k0 = 0; k0 < DD; k0 += 16) {
        float4 xv = *reinterpret_cast<const float4*>(&x[(size_t)(row0 + lr) * DD + k0 + lc]);
        float4 wv;
        if (tid < 128)
            wv = *reinterpret_cast<const float4*>(&Wm[(size_t)(col0 + wr) * DD + k0 + wc]);
        __syncthreads();
        xs[lc + 0][lr] = xv.x; xs[lc + 1][lr] = xv.y; xs[lc + 2][lr] = xv.z; xs[lc + 3][lr] = xv.w;
        if (tid < 128) {
            wsm[wc + 0][wr] = wv.x; wsm[wc + 1][wr] = wv.y; wsm[wc + 2][wr] = wv.z; wsm[wc + 3][wr] = wv.w;
        }
        __syncthreads();
        #pragma unroll
        for (int kk = 0; kk < 16; ++kk) {
            float4 a = *reinterpret_cast<const float4*>(&xs[kk][ty * 4]);
            float2 bb = *reinterpret_cast<const float2*>(&wsm[kk][tx * 2]);
            float av[4] = {a.x, a.y, a.z, a.w};
            #pragma unroll
            for (int mi = 0; mi < 4; ++mi) {
                acc[mi][0] = fmaf(av[mi], bb.x, acc[mi][0]);
                acc[mi][1] = fmaf(av[mi], bb.y, acc[mi][1]);
            }
        }
    }

    #pragma unroll
    for (int mi = 0; mi < 4; ++mi) {
        int n  = row0 + ty * 4 + mi;
        int b_ = n >> 8;
        int s_ = n & 255;
        #pragma unroll
        for (int ni = 0; ni < 2; ++ni) {
            int j = col0 + tx * 2 + ni;           // global output col
            outp[(((size_t)b_ * NH + (j >> 6)) * SS + s_) * WW + (j & 63)] = acc[mi][ni] + bias[j];
        }
    }
}

// ---------------- Fourier attention, v2 ----------------
// thread t owns key t; K row lives in 64 VGPRs (pre-scaled by pi*R).
// V transposed + XOR-swizzled in LDS (64 KB) -> 2 blocks/CU.
// Fixed-shift softmax (scores <= 1, so exp never overflows): no max pass.
__global__ __launch_bounds__(256, 2) void fattn(
    const float* __restrict__ ws,
    const float* __restrict__ mask,
    float* __restrict__ out)
{
    const int bh = blockIdx.y;
    const int b  = bh / NH;
    const int h  = bh - b * NH;
    const int row_base = blockIdx.x * ROWS_B;

    const float* Qg = ws + (size_t)bh * (SS * WW);
    const float* Kg = ws + (size_t)(NB * NH * SS * WW)     + (size_t)bh * (SS * WW);
    const float* Vg = ws + (size_t)(2 * NB * NH * SS * WW) + (size_t)bh * (SS * WW);

    __shared__ __align__(16) float Vt[WW][SS];        // 64 KiB, transposed + swizzled
    __shared__ __align__(16) float Qs[ROWS_B][WW];    // 2 KiB, pre-scaled
    __shared__ __align__(16) float ebuf[2][SS];       // parity-buffered exp values
    __shared__ __align__(16) float ypart[2][4][WW];   // per-wave PV partials
    __shared__ float zpart[2][4];

    const int tid  = threadIdx.x;
    const int lane = tid & 63;
    const int wid  = tid >> 6;

    // ---- K row -> registers (scaled) ----
    float kreg[WW];
    {
        const float4* Kr = reinterpret_cast<const float4*>(Kg + (size_t)tid * WW);
        #pragma unroll
        for (int g = 0; g < 16; ++g) {
            float4 kv = Kr[g];
            kreg[g * 4 + 0] = PIR * kv.x;
            kreg[g * 4 + 1] = PIR * kv.y;
            kreg[g * 4 + 2] = PIR * kv.z;
            kreg[g * 4 + 3] = PIR * kv.w;
        }
    }
    // ---- V -> Vt transposed, XOR-swizzled: logical float4-group gi of row w stored at gi^(w&7) ----
    {
        const float4* Vr = reinterpret_cast<const float4*>(Vg + (size_t)tid * WW);
        const int ig = tid >> 2, io = tid & 3;
        #pragma unroll
        for (int g = 0; g < 16; ++g) {
            float4 vv = Vr[g];
            float vj[4] = {vv.x, vv.y, vv.z, vv.w};
            #pragma unroll
            for (int j = 0; j < 4; ++j) {
                int w = g * 4 + j;
                Vt[w][((ig ^ (w & 7)) << 2) | io] = vj[j];
            }
        }
    }
    // ---- Q rows (scaled) ----
    if (tid < ROWS_B * WW / 4) {
        const float4* Q4 = reinterpret_cast<const float4*>(Qg + (size_t)row_base * WW);
        float4 qv = Q4[tid];
        qv.x *= PIR; qv.y *= PIR; qv.z *= PIR; qv.w *= PIR;
        reinterpret_cast<float4*>(&Qs[0][0])[tid] = qv;
    }
    const float mt = -10000.0f * (1.0f - mask[b * SS + tid]);
    __syncthreads();

    const float4* vt4 = reinterpret_cast<const float4*>(&Vt[lane][0]);
    const int sw = lane & 7;

    for (int l = 0; l < ROWS_B; ++l) {
        const int par = l & 1;

        // ---- score: p = prod_w sinc(pi*R*(q-k))^4, all in registers ----
        float p0 = 1.f, p1 = 1.f;
        const float4* Qr4 = reinterpret_cast<const float4*>(&Qs[l][0]);
        #pragma unroll
        for (int g = 0; g < 16; ++g) {
            float4 q4 = Qr4[g];                      // uniform LDS broadcast
            float qa[4] = {q4.x, q4.y, q4.z, q4.w};
            #pragma unroll
            for (int j = 0; j < 4; ++j) {
                float t = qa[j] - kreg[g * 4 + j];   // = pi*R*(q-k)
                float u = __sinf(t) * __builtin_amdgcn_rcpf(t);
                float u2 = u * u;
                u2 = (fabsf(t) < 1e-30f) ? 1.0f : u2;
                float u4 = u2 * u2;
                if (j & 1) p1 *= u4; else p0 *= u4;
            }
        }
        float e = __expf(p0 * p1 + mt);              // sc <= 1 -> no overflow; masked -> 0

        // ---- wave-local: stash e, partial Z ----
        ebuf[par][tid] = e;
        float z = e;
        #pragma unroll
        for (int off = 32; off; off >>= 1) z += __shfl_xor(z, off);

        // ---- PV partial over own 64-key chunk: lane = output dim w ----
        float y = 0.f;
        const float4* eb4 = reinterpret_cast<const float4*>(&ebuf[par][wid * 64]);
        #pragma unroll
        for (int m = 0; m < 16; ++m) {
            float4 ee = eb4[m];                      // uniform broadcast (own wave's writes)
            float4 vv = vt4[(wid * 16 + m) ^ sw];    // conflict-free swizzled b128
            y = fmaf(ee.x, vv.x, y);
            y = fmaf(ee.y, vv.y, y);
            y = fmaf(ee.z, vv.z, y);
            y = fmaf(ee.w, vv.w, y);
        }
        ypart[par][wid][lane] = y;
        if (lane == 0) zpart[par][wid] = z;
        __syncthreads();

        if (tid < WW) {
            float yy = ypart[par][0][tid] + ypart[par][1][tid]
                     + ypart[par][2][tid] + ypart[par][3][tid];
            float zz = zpart[par][0] + zpart[par][1] + zpart[par][2] + zpart[par][3];
            out[((size_t)b * SS + row_base + l) * DD + h * WW + tid] = yy * __builtin_amdgcn_rcpf(zz);
        }
    }
}

extern "C" void kernel_launch(void* const* d_in, const int* in_sizes, int n_in,
                              void* d_out, int out_size, void* d_ws, size_t ws_size,
                              hipStream_t stream) {
    const float* x    = (const float*)d_in[0];
    const float* mask = (const float*)d_in[1];
    const float* Wq   = (const float*)d_in[2];
    const float* bq   = (const float*)d_in[3];
    const float* Wk   = (const float*)d_in[4];
    const float* bk   = (const float*)d_in[5];
    const float* Wv   = (const float*)d_in[6];
    const float* bv   = (const float*)d_in[7];
    float* out = (float*)d_out;
    float* ws  = (float*)d_ws;    // Q | K | V, each (B,H,S,W) f32

    dim3 g1(NSROWS / 64, DD / 32, 3);     // 576 blocks
    qkv_gemm<<<g1, 256, 0, stream>>>(x, Wq, bq, Wk, bk, Wv, bv, ws);

    dim3 g2(SS / ROWS_B, NB * NH);        // 768 blocks
    fattn<<<g2, 256, 0, stream>>>(ws, mask, out);
}

// Round 3
// 81.962 us; speedup vs baseline: 1.6580x; 1.3534x over previous
//
#include <hip/hip_runtime.h>
#include <math.h>

#define NB 2
#define SS 256
#define DD 768
#define NH 12
#define WW 64

using f32x2  = __attribute__((ext_vector_type(2))) float;
using f32x4  = __attribute__((ext_vector_type(4))) float;
using bf16x8 = __attribute__((ext_vector_type(8))) short;

constexpr float R2  = 0.25f;           // R/2: q,k pre-scale so v_sin input is revolutions
constexpr float C8  = 4.1168160e-7f;   // (2*pi)^-8
constexpr float EPS = 1e-6f;

// ws layout (bytes):
//   qkv f32:  [0, 4718592)            3 * (2*12*256*64) * 4
//   A' bf16:  [4718592, 6291456)      512 rows x 1536 cols (xh | xl)
//   B' bf16:  [6291456, 13369344)     2304 rows x 1536 cols (Wh | Wl)
#define QKV_ELEMS (NB*NH*SS*WW)
#define A_OFF_BYTES 4718592u
#define B_OFF_BYTES 6291456u

__device__ __forceinline__ unsigned short bf16_rn(float f) {
    unsigned u = __builtin_bit_cast(unsigned, f);
    u += 0x7fffu + ((u >> 16) & 1u);
    return (unsigned short)(u >> 16);
}

// ---------------- split conversion: x -> [xh | xl] ----------------
__global__ __launch_bounds__(256) void conv_x(const float* __restrict__ x,
                                              unsigned short* __restrict__ A) {
    int idx = blockIdx.x * 256 + threadIdx.x;          // over 512*768/4
    float4 v = reinterpret_cast<const float4*>(x)[idx];
    int m = idx / (DD/4);
    int c = (idx - m*(DD/4)) * 4;
    float vv[4] = {v.x, v.y, v.z, v.w};
    unsigned short h[4], l[4];
    #pragma unroll
    for (int e = 0; e < 4; ++e) {
        h[e] = bf16_rn(vv[e]);
        float hf = __builtin_bit_cast(float, (unsigned)h[e] << 16);
        l[e] = bf16_rn(vv[e] - hf);
    }
    unsigned short* row = A + (size_t)m * 1536 + c;
    *reinterpret_cast<ushort4*>(row)       = make_ushort4(h[0], h[1], h[2], h[3]);
    *reinterpret_cast<ushort4*>(row + 768) = make_ushort4(l[0], l[1], l[2], l[3]);
}

// ---------------- split conversion: Wq|Wk|Wv -> B' rows [Wh | Wl] ----------------
__global__ __launch_bounds__(256) void conv_w(const float* __restrict__ Wq,
                                              const float* __restrict__ Wk,
                                              const float* __restrict__ Wv,
                                              unsigned short* __restrict__ B) {
    int idx = blockIdx.x * 256 + threadIdx.x;          // over 3*768*192
    int p = idx / (768*192);
    int rem = idx - p*(768*192);
    const float* W = (p == 0) ? Wq : (p == 1) ? Wk : Wv;
    float4 v = reinterpret_cast<const float4*>(W)[rem];
    int j = rem / 192;
    int c = (rem - j*192) * 4;
    float vv[4] = {v.x, v.y, v.z, v.w};
    unsigned short h[4], l[4];
    #pragma unroll
    for (int e = 0; e < 4; ++e) {
        h[e] = bf16_rn(vv[e]);
        float hf = __builtin_bit_cast(float, (unsigned)h[e] << 16);
        l[e] = bf16_rn(vv[e] - hf);
    }
    unsigned short* row = B + (size_t)(p*768 + j) * 1536 + c;
    *reinterpret_cast<ushort4*>(row)       = make_ushort4(h[0], h[1], h[2], h[3]);
    *reinterpret_cast<ushort4*>(row + 768) = make_ushort4(l[0], l[1], l[2], l[3]);
}

// ---------------- split-bf16 MFMA GEMM: C[m][n] = sum_k A'[m][k] B'[n][k] + bias ----------------
// 32x32 tile, 4 waves split-K (3 segments: xh*Wh, xh*Wl, xl*Wh), LDS reduce.
__global__ __launch_bounds__(256, 4) void gemm_qkv(
        const unsigned short* __restrict__ A, const unsigned short* __restrict__ B,
        const float* __restrict__ bq, const float* __restrict__ bk, const float* __restrict__ bv,
        float* __restrict__ qkv) {
    __shared__ float red[4][32*32];
    const int tid = threadIdx.x;
    const int wid = tid >> 6, l = tid & 63;
    const int lr = l & 15, lo_ = l >> 4;
    const int m0 = blockIdx.x * 32, n0 = blockIdx.y * 32;

    const unsigned short* Ap = A + (size_t)(m0 + lr) * 1536 + wid * 192 + lo_ * 8;
    const unsigned short* Bp = B + (size_t)(n0 + lr) * 1536 + wid * 192 + lo_ * 8;

    f32x4 acc00 = 0.f, acc01 = 0.f, acc10 = 0.f, acc11 = 0.f;
    #pragma unroll
    for (int seg = 0; seg < 3; ++seg) {
        const unsigned short* As = Ap + ((seg == 2) ? 768 : 0);   // xl for seg2
        const unsigned short* Bs = Bp + ((seg == 1) ? 768 : 0);   // Wl for seg1
        #pragma unroll
        for (int k = 0; k < 6; ++k) {
            bf16x8 a0 = *reinterpret_cast<const bf16x8*>(As + k*32);
            bf16x8 a1 = *reinterpret_cast<const bf16x8*>(As + 16*1536 + k*32);
            bf16x8 b0 = *reinterpret_cast<const bf16x8*>(Bs + k*32);
            bf16x8 b1 = *reinterpret_cast<const bf16x8*>(Bs + 16*1536 + k*32);
            acc00 = __builtin_amdgcn_mfma_f32_16x16x32_bf16(a0, b0, acc00, 0, 0, 0);
            acc01 = __builtin_amdgcn_mfma_f32_16x16x32_bf16(a0, b1, acc01, 0, 0, 0);
            acc10 = __builtin_amdgcn_mfma_f32_16x16x32_bf16(a1, b0, acc10, 0, 0, 0);
            acc11 = __builtin_amdgcn_mfma_f32_16x16x32_bf16(a1, b1, acc11, 0, 0, 0);
        }
    }
    // D layout (m89-verified): col = lane&15, row = (lane>>4)*4 + reg
    #pragma unroll
    for (int j = 0; j < 4; ++j) {
        int r0 = lo_ * 4 + j;
        red[wid][(r0     ) * 32 + lr     ] = acc00[j];
        red[wid][(r0     ) * 32 + lr + 16] = acc01[j];
        red[wid][(r0 + 16) * 32 + lr     ] = acc10[j];
        red[wid][(r0 + 16) * 32 + lr + 16] = acc11[j];
    }
    __syncthreads();

    int row = tid >> 3, col = (tid & 7) * 4;
    f32x4 s = *reinterpret_cast<f32x4*>(&red[0][row*32 + col]);
    #pragma unroll
    for (int w = 1; w < 4; ++w)
        s += *reinterpret_cast<f32x4*>(&red[w][row*32 + col]);

    int n = n0 + col;
    int which = n / 768;
    int jj = n - which * 768;
    const float* bias = (which == 0) ? bq : (which == 1) ? bk : bv;
    float4 bb = *reinterpret_cast<const float4*>(&bias[jj]);
    s[0] += bb.x; s[1] += bb.y; s[2] += bb.z; s[3] += bb.w;

    int m = m0 + row, b_ = m >> 8, s_ = m & 255;
    int head = jj >> 6, w = jj & 63;
    float* o = qkv + (size_t)which * QKV_ELEMS + (((size_t)b_ * NH + head) * SS + s_) * WW + w;
    *reinterpret_cast<float4*>(o) = make_float4(s[0], s[1], s[2], s[3]);
}

// ---------------- Fourier attention v3 ----------------
// thread = key; K in 64 VGPRs (pre-scaled R/2, revolutions for v_sin).
// 4 Q-rows per block processed simultaneously (packed f32x2 pairs -> v_pk_* ops).
// Grouped-rcp sinc: per 8 dims accumulate prod(sin), prod(|t|); one rcp per group.
// Scores <= 1 -> fixed-shift softmax (no max pass). V read direct from L2.
__global__ __launch_bounds__(256, 4) void fattn(
    const float* __restrict__ qkv, const float* __restrict__ mask, float* __restrict__ out)
{
    const int bh = blockIdx.y;
    const int b = bh / NH, h = bh - b * NH;
    const int row0 = blockIdx.x * 4;

    const float* Qg = qkv + (size_t)bh * (SS * WW);
    const float* Kg = qkv + (size_t)QKV_ELEMS + (size_t)bh * (SS * WW);
    const float* Vg = qkv + (size_t)(2 * QKV_ELEMS) + (size_t)bh * (SS * WW);

    __shared__ f32x2 Qs2[2][WW];      // rows (0,1) and (2,3) packed
    __shared__ f32x4 ebuf[SS];        // per-key exp, 4 rows packed
    __shared__ float ypf[4][WW * 4];  // per-wave PV partials
    __shared__ float zs[4][4];

    const int tid = threadIdx.x, lane = tid & 63, wid = tid >> 6;

    float kreg[WW];
    {
        const float4* Kr = reinterpret_cast<const float4*>(Kg + (size_t)tid * WW);
        #pragma unroll
        for (int g = 0; g < 16; ++g) {
            float4 kv = Kr[g];
            kreg[g*4+0] = R2 * kv.x; kreg[g*4+1] = R2 * kv.y;
            kreg[g*4+2] = R2 * kv.z; kreg[g*4+3] = R2 * kv.w;
        }
    }
    if (tid < 128) {
        int p = tid >> 6, w = tid & 63;
        f32x2 q;
        q[0] = Qg[(row0 + 2*p    ) * WW + w] * R2;
        q[1] = Qg[(row0 + 2*p + 1) * WW + w] * R2;
        Qs2[p][w] = q;
    }
    const float mt = -10000.0f * (1.0f - mask[b * SS + tid]);
    __syncthreads();

    const f32x2 eps2 = EPS;
    float pg0 = 1.f, pg1 = 1.f, pg2 = 1.f, pg3 = 1.f;
    #pragma unroll
    for (int g = 0; g < 8; ++g) {
        f32x2 sp0 = 1.f, sp1 = 1.f, sp2 = 1.f, sp3 = 1.f;   // {prod sin, prod |t|}
        #pragma unroll
        for (int j = 0; j < 8; ++j) {
            float kw = kreg[g*8 + j];
            f32x2 qa = Qs2[0][g*8 + j];
            f32x2 qb = Qs2[1][g*8 + j];
            f32x2 ta = qa - kw;
            f32x2 tb = qb - kw;
            ta = __builtin_elementwise_max(ta, -ta);      // |t| (pk_max w/ neg)
            tb = __builtin_elementwise_max(tb, -tb);
            ta = __builtin_elementwise_max(ta, eps2);     // 0/0 guard (sinc is even)
            tb = __builtin_elementwise_max(tb, eps2);
            float s0 = __builtin_amdgcn_sinf(ta[0]);      // v_sin_f32, revolutions
            float s1 = __builtin_amdgcn_sinf(ta[1]);
            float s2 = __builtin_amdgcn_sinf(tb[0]);
            float s3 = __builtin_amdgcn_sinf(tb[1]);
            f32x2 m0; m0[0] = s0; m0[1] = ta[0];
            f32x2 m1; m1[0] = s1; m1[1] = ta[1];
            f32x2 m2; m2[0] = s2; m2[1] = tb[0];
            f32x2 m3; m3[0] = s3; m3[1] = tb[1];
            sp0 *= m0; sp1 *= m1; sp2 *= m2; sp3 *= m3;   // v_pk_mul
        }
        pg0 *= (sp0[0] * C8) * __builtin_amdgcn_rcpf(sp0[1]);
        pg1 *= (sp1[0] * C8) * __builtin_amdgcn_rcpf(sp1[1]);
        pg2 *= (sp2[0] * C8) * __builtin_amdgcn_rcpf(sp2[1]);
        pg3 *= (sp3[0] * C8) * __builtin_amdgcn_rcpf(sp3[1]);
    }
    pg0 *= pg0; pg0 *= pg0;   // ^4 (sign-safe, underflow benign: exp(tiny)=1 like ref)
    pg1 *= pg1; pg1 *= pg1;
    pg2 *= pg2; pg2 *= pg2;
    pg3 *= pg3; pg3 *= pg3;

    float e0 = __expf(pg0 + mt), e1 = __expf(pg1 + mt);
    float e2 = __expf(pg2 + mt), e3 = __expf(pg3 + mt);
    f32x4 ev; ev[0] = e0; ev[1] = e1; ev[2] = e2; ev[3] = e3;
    ebuf[tid] = ev;

    float z0 = e0, z1 = e1, z2 = e2, z3 = e3;
    #pragma unroll
    for (int off = 32; off; off >>= 1) {
        z0 += __shfl_xor(z0, off);
        z1 += __shfl_xor(z1, off);
        z2 += __shfl_xor(z2, off);
        z3 += __shfl_xor(z3, off);
    }
    if (lane == 0) { zs[wid][0] = z0; zs[wid][1] = z1; zs[wid][2] = z2; zs[wid][3] = z3; }

    // PV: lane = output dim w; wave covers its own 64 keys (ebuf wave-local)
    f32x2 ya = 0.f, yb = 0.f;
    const float* vb = Vg + (size_t)(wid * 64) * WW + lane;
    #pragma unroll 16
    for (int ii = 0; ii < 64; ++ii) {
        float v = vb[ii * WW];
        f32x4 e4 = ebuf[wid * 64 + ii];
        f32x2 ehi; ehi[0] = e4[0]; ehi[1] = e4[1];
        f32x2 elo; elo[0] = e4[2]; elo[1] = e4[3];
        ya += ehi * v;                 // v_pk_fma
        yb += elo * v;
    }
    ypf[wid][lane*4 + 0] = ya[0];
    ypf[wid][lane*4 + 1] = ya[1];
    ypf[wid][lane*4 + 2] = yb[0];
    ypf[wid][lane*4 + 3] = yb[1];
    __syncthreads();

    {
        int r = tid >> 6, w = tid & 63;
        float yy = ypf[0][w*4 + r] + ypf[1][w*4 + r] + ypf[2][w*4 + r] + ypf[3][w*4 + r];
        float zz = zs[0][r] + zs[1][r] + zs[2][r] + zs[3][r];
        out[((size_t)b * SS + row0 + r) * DD + h * WW + w] = yy * __builtin_amdgcn_rcpf(zz);
    }
}

extern "C" void kernel_launch(void* const* d_in, const int* in_sizes, int n_in,
                              void* d_out, int out_size, void* d_ws, size_t ws_size,
                              hipStream_t stream) {
    const float* x    = (const float*)d_in[0];
    const float* mask = (const float*)d_in[1];
    const float* Wq   = (const float*)d_in[2];
    const float* bq   = (const float*)d_in[3];
    const float* Wk   = (const float*)d_in[4];
    const float* bk   = (const float*)d_in[5];
    const float* Wv   = (const float*)d_in[6];
    const float* bv   = (const float*)d_in[7];
    float* out = (float*)d_out;

    float*          qkv = (float*)d_ws;
    unsigned short* Ab  = (unsigned short*)((char*)d_ws + A_OFF_BYTES);
    unsigned short* Bb  = (unsigned short*)((char*)d_ws + B_OFF_BYTES);

    conv_x<<<dim3(512*DD/4/256), 256, 0, stream>>>(x, Ab);
    conv_w<<<dim3(3*DD*DD/4/256), 256, 0, stream>>>(Wq, Wk, Wv, Bb);
    gemm_qkv<<<dim3(512/32, 2304/32), 256, 0, stream>>>(Ab, Bb, bq, bk, bv, qkv);
    fattn<<<dim3(SS/4, NB*NH), 256, 0, stream>>>(qkv, mask, out);
}

// Round 4
// 74.164 us; speedup vs baseline: 1.8324x; 1.1051x over previous
//
#include <hip/hip_runtime.h>
#include <math.h>

#define NB 2
#define SS 256
#define DD 768
#define NH 12
#define WW 64

using f32x2  = __attribute__((ext_vector_type(2))) float;
using f32x4  = __attribute__((ext_vector_type(4))) float;
using bf16x8 = __attribute__((ext_vector_type(8))) short;

constexpr float R2  = 0.25f;           // R/2: q,k pre-scale -> v_sin input in revolutions
constexpr float C8  = 4.1168160e-7f;   // (2*pi)^-8
constexpr float EPS = 1e-4f;           // sinc(|t|<EPS) ~ 1 to 7 digits; keeps group prods normal

// ws layout (bytes):
//   qkv f32:  [0, 4718592)            3 * (2*12*256*64) * 4
//   A' bf16:  [4718592, 6291456)      512 rows x 1536 cols (xh | xl)
//   B' bf16:  [6291456, 13369344)     2304 rows x 1536 cols (Wh | Wl)
#define QKV_ELEMS (NB*NH*SS*WW)
#define A_OFF_BYTES 4718592u
#define B_OFF_BYTES 6291456u

#define XBLKS 384    // 512*768/4/256
#define WBLKS 1728   // 3*768*768/4/256

__device__ __forceinline__ unsigned short bf16_rn(float f) {
    unsigned u = __builtin_bit_cast(unsigned, f);
    u += 0x7fffu + ((u >> 16) & 1u);
    return (unsigned short)(u >> 16);
}

// ---------------- merged split conversions: x -> A' [xh|xl], W -> B' [Wh|Wl] ----------------
__global__ __launch_bounds__(256) void conv_all(
        const float* __restrict__ x,
        const float* __restrict__ Wq, const float* __restrict__ Wk, const float* __restrict__ Wv,
        unsigned short* __restrict__ A, unsigned short* __restrict__ B) {
    int bid = blockIdx.x;
    const float* src;
    unsigned short* dstrow;
    int c;
    if (bid < XBLKS) {
        int idx = bid * 256 + threadIdx.x;           // over 512*768/4
        int m = idx / (DD/4);
        c = (idx - m*(DD/4)) * 4;
        src = x + (size_t)idx * 4;
        dstrow = A + (size_t)m * 1536 + c;
    } else {
        int idx = (bid - XBLKS) * 256 + threadIdx.x; // over 3*768*192
        int p = idx / (768*192);
        int rem = idx - p*(768*192);
        const float* W = (p == 0) ? Wq : (p == 1) ? Wk : Wv;
        int j = rem / 192;
        c = (rem - j*192) * 4;
        src = W + (size_t)rem * 4;
        dstrow = B + (size_t)(p*768 + j) * 1536 + c;
    }
    float4 v = *reinterpret_cast<const float4*>(src);
    float vv[4] = {v.x, v.y, v.z, v.w};
    unsigned short h[4], l[4];
    #pragma unroll
    for (int e = 0; e < 4; ++e) {
        h[e] = bf16_rn(vv[e]);
        float hf = __builtin_bit_cast(float, (unsigned)h[e] << 16);
        l[e] = bf16_rn(vv[e] - hf);
    }
    *reinterpret_cast<ushort4*>(dstrow)       = make_ushort4(h[0], h[1], h[2], h[3]);
    *reinterpret_cast<ushort4*>(dstrow + 768) = make_ushort4(l[0], l[1], l[2], l[3]);
}

// ---------------- split-bf16 MFMA GEMM (unchanged from R3) ----------------
__global__ __launch_bounds__(256, 4) void gemm_qkv(
        const unsigned short* __restrict__ A, const unsigned short* __restrict__ B,
        const float* __restrict__ bq, const float* __restrict__ bk, const float* __restrict__ bv,
        float* __restrict__ qkv) {
    __shared__ float red[4][32*32];
    const int tid = threadIdx.x;
    const int wid = tid >> 6, l = tid & 63;
    const int lr = l & 15, lo_ = l >> 4;
    const int m0 = blockIdx.x * 32, n0 = blockIdx.y * 32;

    const unsigned short* Ap = A + (size_t)(m0 + lr) * 1536 + wid * 192 + lo_ * 8;
    const unsigned short* Bp = B + (size_t)(n0 + lr) * 1536 + wid * 192 + lo_ * 8;

    f32x4 acc00 = 0.f, acc01 = 0.f, acc10 = 0.f, acc11 = 0.f;
    #pragma unroll
    for (int seg = 0; seg < 3; ++seg) {
        const unsigned short* As = Ap + ((seg == 2) ? 768 : 0);
        const unsigned short* Bs = Bp + ((seg == 1) ? 768 : 0);
        #pragma unroll
        for (int k = 0; k < 6; ++k) {
            bf16x8 a0 = *reinterpret_cast<const bf16x8*>(As + k*32);
            bf16x8 a1 = *reinterpret_cast<const bf16x8*>(As + 16*1536 + k*32);
            bf16x8 b0 = *reinterpret_cast<const bf16x8*>(Bs + k*32);
            bf16x8 b1 = *reinterpret_cast<const bf16x8*>(Bs + 16*1536 + k*32);
            acc00 = __builtin_amdgcn_mfma_f32_16x16x32_bf16(a0, b0, acc00, 0, 0, 0);
            acc01 = __builtin_amdgcn_mfma_f32_16x16x32_bf16(a0, b1, acc01, 0, 0, 0);
            acc10 = __builtin_amdgcn_mfma_f32_16x16x32_bf16(a1, b0, acc10, 0, 0, 0);
            acc11 = __builtin_amdgcn_mfma_f32_16x16x32_bf16(a1, b1, acc11, 0, 0, 0);
        }
    }
    #pragma unroll
    for (int j = 0; j < 4; ++j) {
        int r0 = lo_ * 4 + j;
        red[wid][(r0     ) * 32 + lr     ] = acc00[j];
        red[wid][(r0     ) * 32 + lr + 16] = acc01[j];
        red[wid][(r0 + 16) * 32 + lr     ] = acc10[j];
        red[wid][(r0 + 16) * 32 + lr + 16] = acc11[j];
    }
    __syncthreads();

    int row = tid >> 3, col = (tid & 7) * 4;
    f32x4 s = *reinterpret_cast<f32x4*>(&red[0][row*32 + col]);
    #pragma unroll
    for (int w = 1; w < 4; ++w)
        s += *reinterpret_cast<f32x4*>(&red[w][row*32 + col]);

    int n = n0 + col;
    int which = n / 768;
    int jj = n - which * 768;
    const float* bias = (which == 0) ? bq : (which == 1) ? bk : bv;
    float4 bb = *reinterpret_cast<const float4*>(&bias[jj]);
    s[0] += bb.x; s[1] += bb.y; s[2] += bb.z; s[3] += bb.w;

    int m = m0 + row, b_ = m >> 8, s_ = m & 255;
    int head = jj >> 6, w = jj & 63;
    float* o = qkv + (size_t)which * QKV_ELEMS + (((size_t)b_ * NH + head) * SS + s_) * WW + w;
    *reinterpret_cast<float4*>(o) = make_float4(s[0], s[1], s[2], s[3]);
}

// ---------------- Fourier attention v4 ----------------
// thread = key; K in 64 VGPRs. 8 Q rows/block (grid 32x24 = 768 = 3 blocks/CU).
// Sinc in 2 halves of 4 rows; per 8-dim group Q is hoisted to regs via b128
// broadcasts, inner loop is pure-register: sub, max(|t|,eps), sin, 2 muls.
// One rcp per 8 dims. Scores <= 1 -> no max pass. V direct from L2 in PV
// (8 fma per load). Single cross-wave barrier (ypart).
__global__ __launch_bounds__(256, 3) void fattn(
    const float* __restrict__ qkv, const float* __restrict__ mask, float* __restrict__ out)
{
    const int bh = blockIdx.y;
    const int b = bh / NH, h = bh - b * NH;
    const int row0 = blockIdx.x * 8;

    const float* Qg = qkv + (size_t)bh * (SS * WW);
    const float* Kg = qkv + (size_t)QKV_ELEMS + (size_t)bh * (SS * WW);
    const float* Vg = qkv + (size_t)(2 * QKV_ELEMS) + (size_t)bh * (SS * WW);

    __shared__ __align__(16) float Qs[8][WW];        // 2 KB, scaled by R2
    __shared__ __align__(16) float ebuf[SS][8];      // 8 KB
    __shared__ __align__(16) float ypart[4][8][WW];  // 8 KB
    __shared__ float zs[4][8];

    const int tid = threadIdx.x, lane = tid & 63, wid = tid >> 6;

    // ---- K row -> registers (scaled) ----
    float kreg[WW];
    {
        const float4* Kr = reinterpret_cast<const float4*>(Kg + (size_t)tid * WW);
        #pragma unroll
        for (int g = 0; g < 16; ++g) {
            float4 kv = Kr[g];
            kreg[g*4+0] = R2 * kv.x; kreg[g*4+1] = R2 * kv.y;
            kreg[g*4+2] = R2 * kv.z; kreg[g*4+3] = R2 * kv.w;
        }
    }
    // ---- Q rows -> LDS (scaled) ----
    if (tid < 128) {
        float4 qv = reinterpret_cast<const float4*>(Qg + (size_t)row0 * WW)[tid];
        qv.x *= R2; qv.y *= R2; qv.z *= R2; qv.w *= R2;
        reinterpret_cast<float4*>(&Qs[0][0])[tid] = qv;
    }
    const float mt = -10000.0f * (1.0f - mask[b * SS + tid]);
    __syncthreads();

    // ---- sinc scores, two halves of 4 rows (hh runtime to halve code size) ----
    for (int hh = 0; hh < 2; ++hh) {
        float pg[4] = {1.f, 1.f, 1.f, 1.f};
        #pragma unroll
        for (int g = 0; g < 8; ++g) {
            float qr[4][8];
            #pragma unroll
            for (int r = 0; r < 4; ++r) {
                float4 qa = *reinterpret_cast<const float4*>(&Qs[hh*4 + r][g*8]);
                float4 qb = *reinterpret_cast<const float4*>(&Qs[hh*4 + r][g*8 + 4]);
                qr[r][0]=qa.x; qr[r][1]=qa.y; qr[r][2]=qa.z; qr[r][3]=qa.w;
                qr[r][4]=qb.x; qr[r][5]=qb.y; qr[r][6]=qb.z; qr[r][7]=qb.w;
            }
            float ps[4] = {1.f,1.f,1.f,1.f}, pt[4] = {1.f,1.f,1.f,1.f};
            #pragma unroll
            for (int j = 0; j < 8; ++j) {
                float kw = kreg[g*8 + j];
                #pragma unroll
                for (int r = 0; r < 4; ++r) {
                    float t  = qr[r][j] - kw;
                    float at = fmaxf(fabsf(t), EPS);      // 1 instr (abs = src modifier)
                    float s  = __builtin_amdgcn_sinf(at); // sin(2*pi*at) = sin(pi*R*diff)
                    ps[r] *= s;
                    pt[r] *= at;
                }
            }
            #pragma unroll
            for (int r = 0; r < 4; ++r)
                pg[r] *= (ps[r] * C8) * __builtin_amdgcn_rcpf(pt[r]);
        }
        // e = exp(score + maskterm), score = pg^4
        float e[4];
        #pragma unroll
        for (int r = 0; r < 4; ++r) {
            float p = pg[r];
            p *= p; p *= p;
            e[r] = __expf(p + mt);
        }
        f32x4 ev; ev[0]=e[0]; ev[1]=e[1]; ev[2]=e[2]; ev[3]=e[3];
        *reinterpret_cast<f32x4*>(&ebuf[tid][hh*4]) = ev;   // wave-local
        // per-row wave Z reduction
        #pragma unroll
        for (int r = 0; r < 4; ++r) {
            float z = e[r];
            #pragma unroll
            for (int off = 32; off; off >>= 1) z += __shfl_xor(z, off);
            if (lane == 0) zs[wid][hh*4 + r] = z;
        }
    }

    // ---- PV: lane = output dim w; wave covers its own 64 keys (ebuf wave-local) ----
    float y[8] = {0.f,0.f,0.f,0.f,0.f,0.f,0.f,0.f};
    const float* vb = Vg + (size_t)(wid * 64) * WW + lane;
    #pragma unroll 16
    for (int ii = 0; ii < 64; ++ii) {
        float v = vb[ii * WW];
        f32x4 ea = *reinterpret_cast<const f32x4*>(&ebuf[wid*64 + ii][0]); // uniform bcast
        f32x4 eb = *reinterpret_cast<const f32x4*>(&ebuf[wid*64 + ii][4]);
        y[0] = fmaf(ea[0], v, y[0]); y[1] = fmaf(ea[1], v, y[1]);
        y[2] = fmaf(ea[2], v, y[2]); y[3] = fmaf(ea[3], v, y[3]);
        y[4] = fmaf(eb[0], v, y[4]); y[5] = fmaf(eb[1], v, y[5]);
        y[6] = fmaf(eb[2], v, y[6]); y[7] = fmaf(eb[3], v, y[7]);
    }
    #pragma unroll
    for (int r = 0; r < 8; ++r) ypart[wid][r][lane] = y[r];
    __syncthreads();

    // ---- combine 4 waves, divide, write (2 outputs/thread) ----
    {
        const int r0 = tid >> 6;
        #pragma unroll
        for (int q = 0; q < 2; ++q) {
            int rr = r0 + q * 4;
            float yy = ypart[0][rr][lane] + ypart[1][rr][lane]
                     + ypart[2][rr][lane] + ypart[3][rr][lane];
            float zz = zs[0][rr] + zs[1][rr] + zs[2][rr] + zs[3][rr];
            out[((size_t)b * SS + row0 + rr) * DD + h * WW + lane] = yy * __builtin_amdgcn_rcpf(zz);
        }
    }
}

extern "C" void kernel_launch(void* const* d_in, const int* in_sizes, int n_in,
                              void* d_out, int out_size, void* d_ws, size_t ws_size,
                              hipStream_t stream) {
    const float* x    = (const float*)d_in[0];
    const float* mask = (const float*)d_in[1];
    const float* Wq   = (const float*)d_in[2];
    const float* bq   = (const float*)d_in[3];
    const float* Wk   = (const float*)d_in[4];
    const float* bk   = (const float*)d_in[5];
    const float* Wv   = (const float*)d_in[6];
    const float* bv   = (const float*)d_in[7];
    float* out = (float*)d_out;

    float*          qkv = (float*)d_ws;
    unsigned short* Ab  = (unsigned short*)((char*)d_ws + A_OFF_BYTES);
    unsigned short* Bb  = (unsigned short*)((char*)d_ws + B_OFF_BYTES);

    conv_all<<<dim3(XBLKS + WBLKS), 256, 0, stream>>>(x, Wq, Wk, Wv, Ab, Bb);
    gemm_qkv<<<dim3(512/32, 2304/32), 256, 0, stream>>>(Ab, Bb, bq, bk, bv, qkv);
    fattn<<<dim3(SS/8, NB*NH), 256, 0, stream>>>(qkv, mask, out);
}